// Round 8
// baseline (241.788 us; speedup 1.0000x reference)
//
#include <hip/hip_runtime.h>

#define DIM 1024
#define HEADS 16
#define HD 64
#define BATCH 2
#define SEQ 2048
#define MROWS (BATCH*SEQ)   // 4096
#define NQKV (3*DIM)        // 3072
#define BK 32
#define NT (DIM/BK)         // 32 K-tiles
#define KLDT 72             // attn K-tile LDS row stride (u16)
#define VLDT 136            // attn V^T-tile LDS row stride (u16), 128 kv + 8 pad

typedef unsigned short u16;
typedef __attribute__((ext_vector_type(8))) short short8;  // 8 bf16 (4 VGPRs)
typedef __attribute__((ext_vector_type(4))) float f32x4;

#define QSCALE 0.1803368801111204f   // (1/sqrt(64)) * log2(e)
#define DTHR 11.5f                   // defer-max threshold (log2 units ~ e^8)

__device__ __forceinline__ u16 f2bf(float f) {
  unsigned u = __float_as_uint(f);
  u += 0x7FFFu + ((u >> 16) & 1u);   // RNE
  return (u16)(u >> 16);
}

__device__ __forceinline__ unsigned cvtpk(float lo, float hi) {
  unsigned r;
  asm("v_cvt_pk_bf16_f32 %0, %1, %2" : "=v"(r) : "v"(lo), "v"(hi));
  return r;
}

// async global->LDS, 16B per lane. LDS dest must be linear (base + lane*16).
__device__ __forceinline__ void gload16(const u16* g, u16* l) {
  __builtin_amdgcn_global_load_lds((const __attribute__((address_space(1))) unsigned int*)g,
                                   (__attribute__((address_space(3))) unsigned int*)l, 16, 0, 0);
}

// ---------------- fused prep: x->bf16 (2048 blks) + w_qkv^T (3072) + w_out^T (1024) ----
__global__ __launch_bounds__(256) void k_prep(
    const float* __restrict__ x, u16* __restrict__ xb,
    const float* __restrict__ wqkv, u16* __restrict__ oqkv,
    const float* __restrict__ wout, u16* __restrict__ oout) {
  __shared__ float tile[32][33];
  const int bid = blockIdx.x;
  const int tid = threadIdx.x;
  if (bid < 2048) {
    const int i = bid * 256 + tid;                 // 524288 = MROWS*DIM/8 exactly
    const float4* p = (const float4*)x + (size_t)i * 2;
    float4 a = p[0], b = p[1];
    short8 v;
    v[0] = (short)f2bf(a.x); v[1] = (short)f2bf(a.y);
    v[2] = (short)f2bf(a.z); v[3] = (short)f2bf(a.w);
    v[4] = (short)f2bf(b.x); v[5] = (short)f2bf(b.y);
    v[6] = (short)f2bf(b.z); v[7] = (short)f2bf(b.w);
    ((short8*)xb)[i] = v;
    return;
  }
  const float* in; u16* out; int C, c0, r0;
  if (bid < 2048 + 3072) {
    const int idx = bid - 2048;                    // 96 x-tiles, 32 y-tiles
    in = wqkv; out = oqkv; C = NQKV;
    c0 = (idx % 96) * 32; r0 = (idx / 96) * 32;
  } else {
    const int idx = bid - 5120;                    // 32 x 32
    in = wout; out = oout; C = DIM;
    c0 = (idx & 31) * 32; r0 = (idx >> 5) * 32;
  }
  const int tx = tid & 31, ty = tid >> 5;          // (32,8)
#pragma unroll
  for (int i = 0; i < 4; ++i)
    tile[ty + 8 * i][tx] = in[(size_t)(r0 + ty + 8 * i) * C + c0 + tx];
  __syncthreads();
#pragma unroll
  for (int i = 0; i < 4; ++i)
    out[(size_t)(c0 + ty + 8 * i) * DIM + r0 + tx] = f2bf(tile[tx][ty + 8 * i]);
}

// ================= deep-pipelined GEMM core (128x128 tile, 1D grid + XCD swizzle) ======
#define GEMM_PREAMBLE(Aptr, Bptr, GX, NWGS)                                    \
  __shared__ u16 lds_[4 * 8192];                                               \
  const int tid = threadIdx.x;                                                 \
  const int lane = tid & 63;                                                   \
  const int wid = tid >> 6;                                                    \
  const int wm = wid >> 1, wn = wid & 1;                                       \
  const int bid_ = blockIdx.x;                                                 \
  const int wg_ = (bid_ & 7) * ((NWGS) / 8) + (bid_ >> 3);                     \
  const int rowB0 = (wg_ % (GX)) * 128;                                        \
  const int rowA0 = (wg_ / (GX)) * 128;                                        \
  const int rl = lane & 15, lg = lane >> 4;                                    \
  const int csw = (rl >> 1) & 3;                                               \
  const f32x4 fz = {0.f, 0.f, 0.f, 0.f};                                       \
  f32x4 acc[4][4];                                                             \
  _Pragma("unroll") for (int i = 0; i < 4; ++i)                                \
  _Pragma("unroll") for (int j = 0; j < 4; ++j) acc[i][j] = fz;                \
  const int srow = tid >> 2;                                                   \
  const int scol = ((tid & 3) ^ ((tid >> 3) & 3)) * 8;                         \
  const u16* gA = (Aptr) + (size_t)(rowA0 + srow) * DIM + scol;                \
  const u16* gB = (Bptr) + (size_t)(rowB0 + srow) * DIM + scol;                \
  auto stage = [&](int t, int j) {                                             \
    u16* d = lds_ + j * 8192;                                                  \
    gload16(gA + t * BK, d + tid * 8);                                         \
    gload16(gA + (size_t)64 * DIM + t * BK, d + 2048 + tid * 8);               \
    gload16(gB + t * BK, d + 4096 + tid * 8);                                  \
    gload16(gB + (size_t)64 * DIM + t * BK, d + 6144 + tid * 8);               \
  };                                                                           \
  auto compute = [&](int j) {                                                  \
    const u16* bufA = lds_ + j * 8192;                                         \
    const u16* bufB = bufA + 4096;                                             \
    short8 af[4], bfr[4];                                                      \
    _Pragma("unroll") for (int mf = 0; mf < 4; ++mf)                           \
      af[mf] = *(const short8*)(bufA + (wm * 64 + mf * 16 + rl) * 32 +         \
                                ((lg ^ csw) * 8));                             \
    _Pragma("unroll") for (int nf = 0; nf < 4; ++nf)                           \
      bfr[nf] = *(const short8*)(bufB + (wn * 64 + nf * 16 + rl) * 32 +        \
                                 ((lg ^ csw) * 8));                            \
    __builtin_amdgcn_s_setprio(1);                                             \
    _Pragma("unroll") for (int mf = 0; mf < 4; ++mf)                           \
    _Pragma("unroll") for (int nf = 0; nf < 4; ++nf)                           \
      acc[mf][nf] =                                                            \
          __builtin_amdgcn_mfma_f32_16x16x32_bf16(af[mf], bfr[nf],             \
                                                  acc[mf][nf], 0, 0, 0);       \
    __builtin_amdgcn_s_setprio(0);                                             \
  };                                                                           \
  stage(0, 0);                                                                 \
  stage(1, 1);                                                                 \
  stage(2, 2);                                                                 \
  asm volatile("s_waitcnt vmcnt(8)" ::: "memory");                             \
  __builtin_amdgcn_s_barrier();                                                \
  _Pragma("unroll 4") for (int t = 0; t < NT; ++t) {                           \
    if (t + 3 < NT) {                                                          \
      stage(t + 3, (t + 3) & 3);                                               \
      compute(t & 3);                                                          \
      asm volatile("s_waitcnt vmcnt(8)" ::: "memory");                         \
      __builtin_amdgcn_s_barrier();                                            \
    } else if (t == NT - 3) {                                                  \
      compute(t & 3);                                                          \
      asm volatile("s_waitcnt vmcnt(4)" ::: "memory");                         \
      __builtin_amdgcn_s_barrier();                                            \
    } else if (t == NT - 2) {                                                  \
      compute(t & 3);                                                          \
      asm volatile("s_waitcnt vmcnt(0)" ::: "memory");                         \
      __builtin_amdgcn_s_barrier();                                            \
    } else {                                                                   \
      compute(t & 3);                                                          \
    }                                                                          \
  }

// ---------------- QKV GEMM: [4096][1024] @ [1024][3072] (+bias, +pos_bias, +log2e-scale on Q)
__global__ __launch_bounds__(256) void k_gemm_qkv(
    const u16* __restrict__ A, const u16* __restrict__ Bt,
    const float* __restrict__ bias, const float* __restrict__ posb,
    u16* __restrict__ qb, u16* __restrict__ kb, u16* __restrict__ vtb) {
  GEMM_PREAMBLE(A, Bt, 24, 768)

#pragma unroll
  for (int mf = 0; mf < 4; ++mf) {
#pragma unroll
    for (int nf = 0; nf < 4; ++nf) {
#pragma unroll
      for (int r = 0; r < 4; ++r) {
        const int row = rowA0 + wm * 64 + mf * 16 + lg * 4 + r;
        const int col = rowB0 + wn * 64 + nf * 16 + rl;
        float v = acc[mf][nf][r] + bias[col];
        const int which = col >> 10;
        const int within = col & 1023;
        const int h = within >> 6, d = within & 63;
        const int bb = row >> 11, t = row & 2047;
        const size_t bh = (size_t)(bb * HEADS + h);
        if (which == 0) {
          v = (v + posb[within]) * QSCALE;
          qb[(bh * SEQ + t) * HD + d] = f2bf(v);
        } else if (which == 1) {
          kb[(bh * SEQ + t) * HD + d] = f2bf(v);
        } else {
          vtb[(bh * HD + d) * SEQ + t] = f2bf(v);
        }
      }
    }
  }
}

// ---------------- out GEMM: 128x64 tiles, quad-buffered, 1D grid + XCD swizzle ----------
__global__ __launch_bounds__(256) void k_gemm_out(
    const u16* __restrict__ A, const u16* __restrict__ Bt,
    const float* __restrict__ bias, float* __restrict__ out) {
  __shared__ u16 lds_[4 * 6144];
  const int tid = threadIdx.x;
  const int lane = tid & 63;
  const int wid = tid >> 6;
  const int wm = wid >> 1, wn = wid & 1;   // wave tile: 64x32
  const int bid_ = blockIdx.x;
  const int wg_ = (bid_ & 7) * 64 + (bid_ >> 3);   // 512 wgs
  const int rowB0 = (wg_ & 15) * 64;
  const int rowA0 = (wg_ >> 4) * 128;
  const int rl = lane & 15, lg = lane >> 4;
  const int csw = (rl >> 1) & 3;
  const f32x4 fz = {0.f, 0.f, 0.f, 0.f};
  f32x4 acc[4][2];
#pragma unroll
  for (int i = 0; i < 4; ++i)
#pragma unroll
    for (int j = 0; j < 2; ++j) acc[i][j] = fz;
  const int srow = tid >> 2;
  const int scol = ((tid & 3) ^ ((tid >> 3) & 3)) * 8;
  const u16* gA = A + (size_t)(rowA0 + srow) * DIM + scol;
  const u16* gB = Bt + (size_t)(rowB0 + srow) * DIM + scol;  // srow 0..63 valid rows
  auto stage = [&](int t, int j) {
    u16* d = lds_ + j * 6144;
    gload16(gA + t * BK, d + tid * 8);
    gload16(gA + (size_t)64 * DIM + t * BK, d + 2048 + tid * 8);
    gload16(gB + t * BK, d + 4096 + tid * 8);
  };
  auto compute = [&](int j) {
    const u16* bufA = lds_ + j * 6144;
    const u16* bufB = bufA + 4096;
    short8 af[4], bfr[2];
#pragma unroll
    for (int mf = 0; mf < 4; ++mf)
      af[mf] = *(const short8*)(bufA + (wm * 64 + mf * 16 + rl) * 32 + ((lg ^ csw) * 8));
#pragma unroll
    for (int nf = 0; nf < 2; ++nf)
      bfr[nf] = *(const short8*)(bufB + (wn * 32 + nf * 16 + rl) * 32 + ((lg ^ csw) * 8));
    __builtin_amdgcn_s_setprio(1);
#pragma unroll
    for (int mf = 0; mf < 4; ++mf)
#pragma unroll
      for (int nf = 0; nf < 2; ++nf)
        acc[mf][nf] = __builtin_amdgcn_mfma_f32_16x16x32_bf16(af[mf], bfr[nf], acc[mf][nf], 0, 0, 0);
    __builtin_amdgcn_s_setprio(0);
  };
  stage(0, 0);
  stage(1, 1);
  stage(2, 2);
  asm volatile("s_waitcnt vmcnt(6)" ::: "memory");
  __builtin_amdgcn_s_barrier();
#pragma unroll 4
  for (int t = 0; t < NT; ++t) {
    if (t + 3 < NT) {
      stage(t + 3, (t + 3) & 3);
      compute(t & 3);
      asm volatile("s_waitcnt vmcnt(6)" ::: "memory");
      __builtin_amdgcn_s_barrier();
    } else if (t == NT - 3) {
      compute(t & 3);
      asm volatile("s_waitcnt vmcnt(3)" ::: "memory");
      __builtin_amdgcn_s_barrier();
    } else if (t == NT - 2) {
      compute(t & 3);
      asm volatile("s_waitcnt vmcnt(0)" ::: "memory");
      __builtin_amdgcn_s_barrier();
    } else {
      compute(t & 3);
    }
  }

#pragma unroll
  for (int mf = 0; mf < 4; ++mf)
#pragma unroll
    for (int nf = 0; nf < 2; ++nf)
#pragma unroll
      for (int r = 0; r < 4; ++r) {
        const int row = rowA0 + wm * 64 + mf * 16 + lg * 4 + r;
        const int col = rowB0 + wn * 32 + nf * 16 + rl;
        out[(size_t)row * DIM + col] = acc[mf][nf][r] + bias[col];
      }
}

// ---------------- flash attention (causal), KVBLK=128, swapped-QK^T, paired + XCD-affine
// grid = 512: bh = bid&31 (XCD-affine), pair = bid>>5; q-tiles (31-pair) then (pair).
// 17 fat iterations per block (flat across pairs); shuffle P-regroup; dbuf K/V;
// one lgkm-only barrier per iter (global prefetch stays in flight).
__global__ __launch_bounds__(256) void k_attn(
    const u16* __restrict__ qg, const u16* __restrict__ kg, const u16* __restrict__ vg,
    u16* __restrict__ og) {
  __shared__ u16 lK[2][128 * KLDT];   // [kv 0..127][d]
  __shared__ u16 lV[2][64 * VLDT];    // [d][kv 0..127]  (V^T)
  const int tid = threadIdx.x;
  const int lane = tid & 63;
  const int wid = tid >> 6;
  const int rl = lane & 15, lg = lane >> 4;
  const int bh = blockIdx.x & 31;
  const int pair = blockIdx.x >> 5;
  const int b = bh >> 4, h = bh & 15;

  const u16* gK = kg + (size_t)bh * SEQ * HD;
  const u16* gV = vg + (size_t)bh * HD * SEQ;
  const int sr = tid >> 3;          // 0..31
  const int sc = (tid & 7) * 8;     // 0..56
  // P^T regroup shuffle sources
  const int sl0 = (((2 * lg) & 3) << 4) + rl;
  const int sl1 = (((2 * lg + 1) & 3) << 4) + rl;
  const bool hi = (lg >= 2);

#pragma unroll 1
  for (int half = 0; half < 2; ++half) {
    const int qt = half ? pair : (31 - pair);
    const int nt = (qt >> 1) + 1;               // 128-wide kv tiles
    const int qrow = qt * 64 + wid * 16 + rl;   // this lane's q index
    const u16* qptr = qg + ((size_t)bh * SEQ + qrow) * HD + lg * 8;
    const short8 aq0 = *(const short8*)(qptr);
    const short8 aq1 = *(const short8*)(qptr + 32);

    const f32x4 fz = {0.f, 0.f, 0.f, 0.f};
    f32x4 o[4];
#pragma unroll
    for (int dt = 0; dt < 4; ++dt) o[dt] = fz;
    float m = -1e30f, l = 0.f;

    int4 rk[4], rv[4];
    // prologue: tile0 -> regs -> buf0; prefetch tile1 into regs
#pragma unroll
    for (int i = 0; i < 4; ++i) {
      rk[i] = *(const int4*)(gK + (size_t)(i * 32 + sr) * HD + sc);
      rv[i & 1] = rv[i & 1];  // no-op keep order
    }
    rv[0] = *(const int4*)(gV + (size_t)sr * SEQ + sc);
    rv[1] = *(const int4*)(gV + (size_t)sr * SEQ + 64 + sc);
    rv[2] = *(const int4*)(gV + (size_t)(sr + 32) * SEQ + sc);
    rv[3] = *(const int4*)(gV + (size_t)(sr + 32) * SEQ + 64 + sc);
#pragma unroll
    for (int i = 0; i < 4; ++i)
      *(int4*)(lK[0] + (i * 32 + sr) * KLDT + sc) = rk[i];
    *(int4*)(lV[0] + sr * VLDT + sc) = rv[0];
    *(int4*)(lV[0] + sr * VLDT + 64 + sc) = rv[1];
    *(int4*)(lV[0] + (sr + 32) * VLDT + sc) = rv[2];
    *(int4*)(lV[0] + (sr + 32) * VLDT + 64 + sc) = rv[3];
    if (nt > 1) {
#pragma unroll
      for (int i = 0; i < 4; ++i)
        rk[i] = *(const int4*)(gK + (size_t)(128 + i * 32 + sr) * HD + sc);
      rv[0] = *(const int4*)(gV + (size_t)sr * SEQ + 128 + sc);
      rv[1] = *(const int4*)(gV + (size_t)sr * SEQ + 192 + sc);
      rv[2] = *(const int4*)(gV + (size_t)(sr + 32) * SEQ + 128 + sc);
      rv[3] = *(const int4*)(gV + (size_t)(sr + 32) * SEQ + 192 + sc);
    }
    asm volatile("s_waitcnt lgkmcnt(0)" ::: "memory");
    __builtin_amdgcn_s_barrier();

    for (int kt = 0; kt < nt; ++kt) {
      const int cur = kt & 1;
      // stage tile kt+1 into alternate buffer; prefetch tile kt+2 into regs
      if (kt + 1 < nt) {
        u16* dK = lK[cur ^ 1];
        u16* dV = lV[cur ^ 1];
#pragma unroll
        for (int i = 0; i < 4; ++i)
          *(int4*)(dK + (i * 32 + sr) * KLDT + sc) = rk[i];
        *(int4*)(dV + sr * VLDT + sc) = rv[0];
        *(int4*)(dV + sr * VLDT + 64 + sc) = rv[1];
        *(int4*)(dV + (sr + 32) * VLDT + sc) = rv[2];
        *(int4*)(dV + (sr + 32) * VLDT + 64 + sc) = rv[3];
        if (kt + 2 < nt) {
          const int kv2 = (kt + 2) * 128;
#pragma unroll
          for (int i = 0; i < 4; ++i)
            rk[i] = *(const int4*)(gK + (size_t)(kv2 + i * 32 + sr) * HD + sc);
          rv[0] = *(const int4*)(gV + (size_t)sr * SEQ + kv2 + sc);
          rv[1] = *(const int4*)(gV + (size_t)sr * SEQ + kv2 + 64 + sc);
          rv[2] = *(const int4*)(gV + (size_t)(sr + 32) * SEQ + kv2 + sc);
          rv[3] = *(const int4*)(gV + (size_t)(sr + 32) * SEQ + kv2 + 64 + sc);
        }
      }
      const u16* bK = lK[cur];
      const u16* bV = lV[cur];
      const int kv0 = kt * 128;

      // S^T = K Q^T : lane holds S[q=rl][kv = kv0 + ct*16 + lg*4 + r], ct 0..7
      f32x4 s[8];
#pragma unroll
      for (int ct = 0; ct < 8; ++ct) s[ct] = fz;
      __builtin_amdgcn_s_setprio(1);
#pragma unroll
      for (int ct = 0; ct < 8; ++ct) {
        short8 ak0 = *(const short8*)(bK + (ct * 16 + rl) * KLDT + lg * 8);
        short8 ak1 = *(const short8*)(bK + (ct * 16 + rl) * KLDT + 32 + lg * 8);
        s[ct] = __builtin_amdgcn_mfma_f32_16x16x32_bf16(ak0, aq0, s[ct], 0, 0, 0);
        s[ct] = __builtin_amdgcn_mfma_f32_16x16x32_bf16(ak1, aq1, s[ct], 0, 0, 0);
      }
      __builtin_amdgcn_s_setprio(0);

      if (kt == nt - 1) {   // diagonal region: causal mask
#pragma unroll
        for (int ct = 0; ct < 8; ++ct)
#pragma unroll
          for (int r = 0; r < 4; ++r)
            if (kv0 + ct * 16 + lg * 4 + r > qrow) s[ct][r] = -1e30f;
      }

      // tree max
      float cm[8];
#pragma unroll
      for (int ct = 0; ct < 8; ++ct)
        cm[ct] = fmaxf(fmaxf(s[ct][0], s[ct][1]), fmaxf(s[ct][2], s[ct][3]));
      float pmax = fmaxf(fmaxf(fmaxf(cm[0], cm[1]), fmaxf(cm[2], cm[3])),
                         fmaxf(fmaxf(cm[4], cm[5]), fmaxf(cm[6], cm[7])));
      pmax = fmaxf(pmax, __shfl_xor(pmax, 16, 64));
      pmax = fmaxf(pmax, __shfl_xor(pmax, 32, 64));

      // defer-max (T13)
      if (__any(pmax - m > DTHR)) {
        const float mn = fmaxf(m, pmax);
        const float alpha = __builtin_amdgcn_exp2f(m - mn);
        m = mn;
        l *= alpha;
#pragma unroll
        for (int dt = 0; dt < 4; ++dt)
#pragma unroll
          for (int r = 0; r < 4; ++r) o[dt][r] *= alpha;
      }

      float rc[8];
      unsigned pk[8][2];
#pragma unroll
      for (int ct = 0; ct < 8; ++ct) {
        float p0 = __builtin_amdgcn_exp2f(s[ct][0] - m);
        float p1 = __builtin_amdgcn_exp2f(s[ct][1] - m);
        float p2 = __builtin_amdgcn_exp2f(s[ct][2] - m);
        float p3 = __builtin_amdgcn_exp2f(s[ct][3] - m);
        rc[ct] = (p0 + p1) + (p2 + p3);
        pk[ct][0] = cvtpk(p0, p1);
        pk[ct][1] = cvtpk(p2, p3);
      }
      l += ((rc[0] + rc[1]) + (rc[2] + rc[3])) + ((rc[4] + rc[5]) + (rc[6] + rc[7]));

      // O^T += V^T P^T : regroup P (4-strided) -> B-frag (8-contig) via shuffles
#pragma unroll
      for (int kb2 = 0; kb2 < 4; ++kb2) {
        unsigned a0 = (unsigned)__shfl((int)pk[2 * kb2 + 0][0], sl0, 64);
        unsigned b0 = (unsigned)__shfl((int)pk[2 * kb2 + 1][0], sl0, 64);
        unsigned a1 = (unsigned)__shfl((int)pk[2 * kb2 + 0][1], sl0, 64);
        unsigned b1 = (unsigned)__shfl((int)pk[2 * kb2 + 1][1], sl0, 64);
        unsigned a2 = (unsigned)__shfl((int)pk[2 * kb2 + 0][0], sl1, 64);
        unsigned b2 = (unsigned)__shfl((int)pk[2 * kb2 + 1][0], sl1, 64);
        unsigned a3 = (unsigned)__shfl((int)pk[2 * kb2 + 0][1], sl1, 64);
        unsigned b3 = (unsigned)__shfl((int)pk[2 * kb2 + 1][1], sl1, 64);
        union { unsigned u[4]; short8 s8; } pu;
        pu.u[0] = hi ? b0 : a0;
        pu.u[1] = hi ? b1 : a1;
        pu.u[2] = hi ? b2 : a2;
        pu.u[3] = hi ? b3 : a3;
        __builtin_amdgcn_s_setprio(1);
#pragma unroll
        for (int dt = 0; dt < 4; ++dt) {
          short8 av = *(const short8*)(bV + (dt * 16 + rl) * VLDT + kb2 * 32 + lg * 8);
          o[dt] = __builtin_amdgcn_mfma_f32_16x16x32_bf16(av, pu.s8, o[dt], 0, 0, 0);
        }
        __builtin_amdgcn_s_setprio(0);
      }

      // one barrier per iter; lgkm only -> global prefetch stays in flight
      asm volatile("s_waitcnt lgkmcnt(0)" ::: "memory");
      __builtin_amdgcn_s_barrier();
    }

    // epilogue: finish deferred l-reduction, normalize, write O
    l += __shfl_xor(l, 16, 64);
    l += __shfl_xor(l, 32, 64);
    const float linv = __builtin_amdgcn_rcpf(l);
    const size_t obase = ((size_t)b * SEQ + qrow) * DIM + h * HD;
#pragma unroll
    for (int dt = 0; dt < 4; ++dt) {
      uint2 w;
      w.x = cvtpk(o[dt][0] * linv, o[dt][1] * linv);
      w.y = cvtpk(o[dt][2] * linv, o[dt][3] * linv);
      *(uint2*)(og + obase + dt * 16 + lg * 4) = w;
    }
  }
}

extern "C" void kernel_launch(void* const* d_in, const int* in_sizes, int n_in,
                              void* d_out, int out_size, void* d_ws, size_t ws_size,
                              hipStream_t stream) {
  const float* x = (const float*)d_in[0];
  const float* w_qkv = (const float*)d_in[1];
  const float* b_qkv = (const float*)d_in[2];
  const float* w_out = (const float*)d_in[3];
  const float* b_out = (const float*)d_in[4];
  const float* pos_bias = (const float*)d_in[5];
  float* out = (float*)d_out;

  u16* ws = (u16*)d_ws;
  u16* xb = ws;                                           // 4096*1024
  u16* wqkvb = xb + (size_t)MROWS * DIM;                  // 3072*1024 (w_qkv^T)
  u16* woutb = wqkvb + (size_t)NQKV * DIM;                // 1024*1024 (w_out^T)
  u16* qb = woutb + (size_t)DIM * DIM;                    // [b,h,t,d] (pre-scaled)
  u16* kbuf = qb + (size_t)BATCH * HEADS * SEQ * HD;      // [b,h,t,d]
  u16* vtb = kbuf + (size_t)BATCH * HEADS * SEQ * HD;     // [b,h,d,t]
  u16* attnb = xb;  // alias: xb dead after k_gemm_qkv (stream-serialized)

  k_prep<<<6144, 256, 0, stream>>>(x, xb, w_qkv, wqkvb, w_out, woutb);
  k_gemm_qkv<<<768, 256, 0, stream>>>(xb, wqkvb, b_qkv, pos_bias, qb, kbuf, vtb);
  k_attn<<<dim3(BATCH * HEADS * 16), 256, 0, stream>>>(qb, kbuf, vtb, attnb);
  k_gemm_out<<<512, 256, 0, stream>>>(attnb, woutb, b_out, out);
}

// Round 9
// 194.695 us; speedup vs baseline: 1.2419x; 1.2419x over previous
//
#include <hip/hip_runtime.h>

#define DIM 1024
#define HEADS 16
#define HD 64
#define BATCH 2
#define SEQ 2048
#define MROWS (BATCH*SEQ)   // 4096
#define NQKV (3*DIM)        // 3072
#define BK 32
#define NT (DIM/BK)         // 32 K-tiles
#define ALDT 72             // attn LDS row stride (u16)

typedef unsigned short u16;
typedef __attribute__((ext_vector_type(8))) short short8;  // 8 bf16 (4 VGPRs)
typedef __attribute__((ext_vector_type(4))) float f32x4;

#define QSCALE 0.1803368801111204f   // (1/sqrt(64)) * log2(e)
#define DTHR 11.5f                   // defer-max threshold (log2 units ~ e^8)

__device__ __forceinline__ u16 f2bf(float f) {
  unsigned u = __float_as_uint(f);
  u += 0x7FFFu + ((u >> 16) & 1u);   // RNE
  return (u16)(u >> 16);
}

__device__ __forceinline__ unsigned cvtpk(float lo, float hi) {
  unsigned r;
  asm("v_cvt_pk_bf16_f32 %0, %1, %2" : "=v"(r) : "v"(lo), "v"(hi));
  return r;
}

// async global->LDS, 16B per lane. LDS dest must be linear (base + lane*16).
__device__ __forceinline__ void gload16(const u16* g, u16* l) {
  __builtin_amdgcn_global_load_lds((const __attribute__((address_space(1))) unsigned int*)g,
                                   (__attribute__((address_space(3))) unsigned int*)l, 16, 0, 0);
}

// ---------------- fused prep: x->bf16 (2048 blks) + w_qkv^T (3072) + w_out^T (1024) ----
__global__ __launch_bounds__(256) void k_prep(
    const float* __restrict__ x, u16* __restrict__ xb,
    const float* __restrict__ wqkv, u16* __restrict__ oqkv,
    const float* __restrict__ wout, u16* __restrict__ oout) {
  __shared__ float tile[32][33];
  const int bid = blockIdx.x;
  const int tid = threadIdx.x;
  if (bid < 2048) {
    const int i = bid * 256 + tid;                 // 524288 = MROWS*DIM/8 exactly
    const float4* p = (const float4*)x + (size_t)i * 2;
    float4 a = p[0], b = p[1];
    short8 v;
    v[0] = (short)f2bf(a.x); v[1] = (short)f2bf(a.y);
    v[2] = (short)f2bf(a.z); v[3] = (short)f2bf(a.w);
    v[4] = (short)f2bf(b.x); v[5] = (short)f2bf(b.y);
    v[6] = (short)f2bf(b.z); v[7] = (short)f2bf(b.w);
    ((short8*)xb)[i] = v;
    return;
  }
  const float* in; u16* out; int C, c0, r0;
  if (bid < 2048 + 3072) {
    const int idx = bid - 2048;                    // 96 x-tiles, 32 y-tiles
    in = wqkv; out = oqkv; C = NQKV;
    c0 = (idx % 96) * 32; r0 = (idx / 96) * 32;
  } else {
    const int idx = bid - 5120;                    // 32 x 32
    in = wout; out = oout; C = DIM;
    c0 = (idx & 31) * 32; r0 = (idx >> 5) * 32;
  }
  const int tx = tid & 31, ty = tid >> 5;          // (32,8)
#pragma unroll
  for (int i = 0; i < 4; ++i)
    tile[ty + 8 * i][tx] = in[(size_t)(r0 + ty + 8 * i) * C + c0 + tx];
  __syncthreads();
#pragma unroll
  for (int i = 0; i < 4; ++i)
    out[(size_t)(c0 + ty + 8 * i) * DIM + r0 + tx] = f2bf(tile[tx][ty + 8 * i]);
}

// ================= deep-pipelined GEMM core (128x128 tile, 1D grid + XCD swizzle) ======
#define GEMM_PREAMBLE(Aptr, Bptr, GX, NWGS)                                    \
  __shared__ u16 lds_[4 * 8192];                                               \
  const int tid = threadIdx.x;                                                 \
  const int lane = tid & 63;                                                   \
  const int wid = tid >> 6;                                                    \
  const int wm = wid >> 1, wn = wid & 1;                                       \
  const int bid_ = blockIdx.x;                                                 \
  const int wg_ = (bid_ & 7) * ((NWGS) / 8) + (bid_ >> 3);                     \
  const int rowB0 = (wg_ % (GX)) * 128;                                        \
  const int rowA0 = (wg_ / (GX)) * 128;                                        \
  const int rl = lane & 15, lg = lane >> 4;                                    \
  const int csw = (rl >> 1) & 3;                                               \
  const f32x4 fz = {0.f, 0.f, 0.f, 0.f};                                       \
  f32x4 acc[4][4];                                                             \
  _Pragma("unroll") for (int i = 0; i < 4; ++i)                                \
  _Pragma("unroll") for (int j = 0; j < 4; ++j) acc[i][j] = fz;                \
  const int srow = tid >> 2;                                                   \
  const int scol = ((tid & 3) ^ ((tid >> 3) & 3)) * 8;                         \
  const u16* gA = (Aptr) + (size_t)(rowA0 + srow) * DIM + scol;                \
  const u16* gB = (Bptr) + (size_t)(rowB0 + srow) * DIM + scol;                \
  auto stage = [&](int t, int j) {                                             \
    u16* d = lds_ + j * 8192;                                                  \
    gload16(gA + t * BK, d + tid * 8);                                         \
    gload16(gA + (size_t)64 * DIM + t * BK, d + 2048 + tid * 8);               \
    gload16(gB + t * BK, d + 4096 + tid * 8);                                  \
    gload16(gB + (size_t)64 * DIM + t * BK, d + 6144 + tid * 8);               \
  };                                                                           \
  auto compute = [&](int j) {                                                  \
    const u16* bufA = lds_ + j * 8192;                                         \
    const u16* bufB = bufA + 4096;                                             \
    short8 af[4], bfr[4];                                                      \
    _Pragma("unroll") for (int mf = 0; mf < 4; ++mf)                           \
      af[mf] = *(const short8*)(bufA + (wm * 64 + mf * 16 + rl) * 32 +         \
                                ((lg ^ csw) * 8));                             \
    _Pragma("unroll") for (int nf = 0; nf < 4; ++nf)                           \
      bfr[nf] = *(const short8*)(bufB + (wn * 64 + nf * 16 + rl) * 32 +        \
                                 ((lg ^ csw) * 8));                            \
    __builtin_amdgcn_s_setprio(1);                                             \
    _Pragma("unroll") for (int mf = 0; mf < 4; ++mf)                           \
    _Pragma("unroll") for (int nf = 0; nf < 4; ++nf)                           \
      acc[mf][nf] =                                                            \
          __builtin_amdgcn_mfma_f32_16x16x32_bf16(af[mf], bfr[nf],             \
                                                  acc[mf][nf], 0, 0, 0);       \
    __builtin_amdgcn_s_setprio(0);                                             \
  };                                                                           \
  stage(0, 0);                                                                 \
  stage(1, 1);                                                                 \
  stage(2, 2);                                                                 \
  asm volatile("s_waitcnt vmcnt(8)" ::: "memory");                             \
  __builtin_amdgcn_s_barrier();                                                \
  _Pragma("unroll 4") for (int t = 0; t < NT; ++t) {                           \
    if (t + 3 < NT) {                                                          \
      stage(t + 3, (t + 3) & 3);                                               \
      compute(t & 3);                                                          \
      asm volatile("s_waitcnt vmcnt(8)" ::: "memory");                         \
      __builtin_amdgcn_s_barrier();                                            \
    } else if (t == NT - 3) {                                                  \
      compute(t & 3);                                                          \
      asm volatile("s_waitcnt vmcnt(4)" ::: "memory");                         \
      __builtin_amdgcn_s_barrier();                                            \
    } else if (t == NT - 2) {                                                  \
      compute(t & 3);                                                          \
      asm volatile("s_waitcnt vmcnt(0)" ::: "memory");                         \
      __builtin_amdgcn_s_barrier();                                            \
    } else {                                                                   \
      compute(t & 3);                                                          \
    }                                                                          \
  }

// ---------------- QKV GEMM: [4096][1024] @ [1024][3072] (+bias, +pos_bias, +log2e-scale on Q)
__global__ __launch_bounds__(256) void k_gemm_qkv(
    const u16* __restrict__ A, const u16* __restrict__ Bt,
    const float* __restrict__ bias, const float* __restrict__ posb,
    u16* __restrict__ qb, u16* __restrict__ kb, u16* __restrict__ vtb) {
  GEMM_PREAMBLE(A, Bt, 24, 768)

#pragma unroll
  for (int mf = 0; mf < 4; ++mf) {
#pragma unroll
    for (int nf = 0; nf < 4; ++nf) {
#pragma unroll
      for (int r = 0; r < 4; ++r) {
        const int row = rowA0 + wm * 64 + mf * 16 + lg * 4 + r;
        const int col = rowB0 + wn * 64 + nf * 16 + rl;
        float v = acc[mf][nf][r] + bias[col];
        const int which = col >> 10;
        const int within = col & 1023;
        const int h = within >> 6, d = within & 63;
        const int bb = row >> 11, t = row & 2047;
        const size_t bh = (size_t)(bb * HEADS + h);
        if (which == 0) {
          v = (v + posb[within]) * QSCALE;
          qb[(bh * SEQ + t) * HD + d] = f2bf(v);
        } else if (which == 1) {
          kb[(bh * SEQ + t) * HD + d] = f2bf(v);
        } else {
          vtb[(bh * HD + d) * SEQ + t] = f2bf(v);
        }
      }
    }
  }
}

// ---------------- out GEMM: 128x64 tiles, quad-buffered, 1D grid + XCD swizzle ----------
__global__ __launch_bounds__(256) void k_gemm_out(
    const u16* __restrict__ A, const u16* __restrict__ Bt,
    const float* __restrict__ bias, float* __restrict__ out) {
  __shared__ u16 lds_[4 * 6144];
  const int tid = threadIdx.x;
  const int lane = tid & 63;
  const int wid = tid >> 6;
  const int wm = wid >> 1, wn = wid & 1;   // wave tile: 64x32
  const int bid_ = blockIdx.x;
  const int wg_ = (bid_ & 7) * 64 + (bid_ >> 3);   // 512 wgs
  const int rowB0 = (wg_ & 15) * 64;
  const int rowA0 = (wg_ >> 4) * 128;
  const int rl = lane & 15, lg = lane >> 4;
  const int csw = (rl >> 1) & 3;
  const f32x4 fz = {0.f, 0.f, 0.f, 0.f};
  f32x4 acc[4][2];
#pragma unroll
  for (int i = 0; i < 4; ++i)
#pragma unroll
    for (int j = 0; j < 2; ++j) acc[i][j] = fz;
  const int srow = tid >> 2;
  const int scol = ((tid & 3) ^ ((tid >> 3) & 3)) * 8;
  const u16* gA = A + (size_t)(rowA0 + srow) * DIM + scol;
  const u16* gB = Bt + (size_t)(rowB0 + srow) * DIM + scol;  // srow 0..63 valid rows
  auto stage = [&](int t, int j) {
    u16* d = lds_ + j * 6144;
    gload16(gA + t * BK, d + tid * 8);
    gload16(gA + (size_t)64 * DIM + t * BK, d + 2048 + tid * 8);
    gload16(gB + t * BK, d + 4096 + tid * 8);
  };
  auto compute = [&](int j) {
    const u16* bufA = lds_ + j * 6144;
    const u16* bufB = bufA + 4096;
    short8 af[4], bfr[2];
#pragma unroll
    for (int mf = 0; mf < 4; ++mf)
      af[mf] = *(const short8*)(bufA + (wm * 64 + mf * 16 + rl) * 32 + ((lg ^ csw) * 8));
#pragma unroll
    for (int nf = 0; nf < 2; ++nf)
      bfr[nf] = *(const short8*)(bufB + (wn * 32 + nf * 16 + rl) * 32 + ((lg ^ csw) * 8));
    __builtin_amdgcn_s_setprio(1);
#pragma unroll
    for (int mf = 0; mf < 4; ++mf)
#pragma unroll
      for (int nf = 0; nf < 2; ++nf)
        acc[mf][nf] = __builtin_amdgcn_mfma_f32_16x16x32_bf16(af[mf], bfr[nf], acc[mf][nf], 0, 0, 0);
    __builtin_amdgcn_s_setprio(0);
  };
  stage(0, 0);
  stage(1, 1);
  stage(2, 2);
  asm volatile("s_waitcnt vmcnt(6)" ::: "memory");
  __builtin_amdgcn_s_barrier();
#pragma unroll 4
  for (int t = 0; t < NT; ++t) {
    if (t + 3 < NT) {
      stage(t + 3, (t + 3) & 3);
      compute(t & 3);
      asm volatile("s_waitcnt vmcnt(6)" ::: "memory");
      __builtin_amdgcn_s_barrier();
    } else if (t == NT - 3) {
      compute(t & 3);
      asm volatile("s_waitcnt vmcnt(3)" ::: "memory");
      __builtin_amdgcn_s_barrier();
    } else if (t == NT - 2) {
      compute(t & 3);
      asm volatile("s_waitcnt vmcnt(0)" ::: "memory");
      __builtin_amdgcn_s_barrier();
    } else {
      compute(t & 3);
    }
  }

#pragma unroll
  for (int mf = 0; mf < 4; ++mf)
#pragma unroll
    for (int nf = 0; nf < 2; ++nf)
#pragma unroll
      for (int r = 0; r < 4; ++r) {
        const int row = rowA0 + wm * 64 + mf * 16 + lg * 4 + r;
        const int col = rowB0 + wn * 32 + nf * 16 + rl;
        out[(size_t)row * DIM + col] = acc[mf][nf][r] + bias[col];
      }
}

// ---------------- flash attention (causal), swapped-QK^T, paired + XCD-affine ----------
// R7-proven structure: KVBLK=64, dbuf K/V, lP regroup, one lgkm-only barrier/iter.
__global__ __launch_bounds__(256) void k_attn(
    const u16* __restrict__ qg, const u16* __restrict__ kg, const u16* __restrict__ vg,
    u16* __restrict__ og) {
  __shared__ u16 lK[2][64 * ALDT];   // [kv][d]
  __shared__ u16 lV[2][64 * ALDT];   // [d][kv]  (V^T)
  __shared__ u16 lP[4 * 16 * ALDT];  // wave-private P^T regroup buffers
  const int tid = threadIdx.x;
  const int lane = tid & 63;
  const int wid = tid >> 6;
  const int rl = lane & 15, lg = lane >> 4;
  const int bh = blockIdx.x & 31;
  const int pair = blockIdx.x >> 5;
  const int b = bh >> 4, h = bh & 15;

  const u16* gK = kg + (size_t)bh * SEQ * HD;
  const u16* gV = vg + (size_t)bh * HD * SEQ;
  const int sr = tid >> 3;          // 0..31
  const int sc = (tid & 7) * 8;     // 0..56
  u16* pw = lP + wid * 16 * ALDT;

#pragma unroll 1
  for (int half = 0; half < 2; ++half) {
    const int qt = half ? pair : (31 - pair);
    const int qrow = qt * 64 + wid * 16 + rl;   // this lane's q index
    const u16* qptr = qg + ((size_t)bh * SEQ + qrow) * HD + lg * 8;
    const short8 aq0 = *(const short8*)(qptr);
    const short8 aq1 = *(const short8*)(qptr + 32);

    const f32x4 fz = {0.f, 0.f, 0.f, 0.f};
    f32x4 o[4];
#pragma unroll
    for (int dt = 0; dt < 4; ++dt) o[dt] = fz;
    float m = -1e30f, l = 0.f;

    // prologue: tile0 -> buf0; prefetch tile1 into regs
    int4 rka = *(const int4*)(gK + (size_t)sr * HD + sc);
    int4 rkb = *(const int4*)(gK + (size_t)(sr + 32) * HD + sc);
    int4 rva = *(const int4*)(gV + (size_t)sr * SEQ + sc);
    int4 rvb = *(const int4*)(gV + (size_t)(sr + 32) * SEQ + sc);
    *(int4*)(lK[0] + sr * ALDT + sc) = rka;
    *(int4*)(lK[0] + (sr + 32) * ALDT + sc) = rkb;
    *(int4*)(lV[0] + sr * ALDT + sc) = rva;
    *(int4*)(lV[0] + (sr + 32) * ALDT + sc) = rvb;
    if (qt > 0) {
      rka = *(const int4*)(gK + (size_t)(64 + sr) * HD + sc);
      rkb = *(const int4*)(gK + (size_t)(64 + sr + 32) * HD + sc);
      rva = *(const int4*)(gV + (size_t)sr * SEQ + 64 + sc);
      rvb = *(const int4*)(gV + (size_t)(sr + 32) * SEQ + 64 + sc);
    }
    asm volatile("s_waitcnt lgkmcnt(0)" ::: "memory");
    __builtin_amdgcn_s_barrier();

    for (int kt = 0; kt <= qt; ++kt) {
      const int cur = kt & 1;
      // stage tile kt+1 into alternate buffer; prefetch tile kt+2 into regs
      if (kt < qt) {
        u16* dK = lK[cur ^ 1];
        u16* dV = lV[cur ^ 1];
        *(int4*)(dK + sr * ALDT + sc) = rka;
        *(int4*)(dK + (sr + 32) * ALDT + sc) = rkb;
        *(int4*)(dV + sr * ALDT + sc) = rva;
        *(int4*)(dV + (sr + 32) * ALDT + sc) = rvb;
        if (kt + 2 <= qt) {
          const int kv2 = (kt + 2) * 64;
          rka = *(const int4*)(gK + (size_t)(kv2 + sr) * HD + sc);
          rkb = *(const int4*)(gK + (size_t)(kv2 + sr + 32) * HD + sc);
          rva = *(const int4*)(gV + (size_t)sr * SEQ + kv2 + sc);
          rvb = *(const int4*)(gV + (size_t)(sr + 32) * SEQ + kv2 + sc);
        }
      }
      const u16* bK = lK[cur];
      const u16* bV = lV[cur];

      // S^T = K Q^T : lane holds S[q=rl][kv = ct*16 + lg*4 + r]
      f32x4 s[4];
#pragma unroll
      for (int ct = 0; ct < 4; ++ct) s[ct] = fz;
      __builtin_amdgcn_s_setprio(1);
#pragma unroll
      for (int ct = 0; ct < 4; ++ct) {
        short8 ak0 = *(const short8*)(bK + (ct * 16 + rl) * ALDT + lg * 8);
        short8 ak1 = *(const short8*)(bK + (ct * 16 + rl) * ALDT + 32 + lg * 8);
        s[ct] = __builtin_amdgcn_mfma_f32_16x16x32_bf16(ak0, aq0, s[ct], 0, 0, 0);
        s[ct] = __builtin_amdgcn_mfma_f32_16x16x32_bf16(ak1, aq1, s[ct], 0, 0, 0);
      }
      __builtin_amdgcn_s_setprio(0);

      if (kt == qt) {   // diagonal tile: causal mask
#pragma unroll
        for (int ct = 0; ct < 4; ++ct)
#pragma unroll
          for (int r = 0; r < 4; ++r)
            if (kt * 64 + ct * 16 + lg * 4 + r > qrow) s[ct][r] = -1e30f;
      }

      // tree max (depth 4)
      float cm[4];
#pragma unroll
      for (int ct = 0; ct < 4; ++ct)
        cm[ct] = fmaxf(fmaxf(s[ct][0], s[ct][1]), fmaxf(s[ct][2], s[ct][3]));
      float pmax = fmaxf(fmaxf(cm[0], cm[1]), fmaxf(cm[2], cm[3]));
      pmax = fmaxf(pmax, __shfl_xor(pmax, 16, 64));
      pmax = fmaxf(pmax, __shfl_xor(pmax, 32, 64));

      // defer-max (T13): only rescale when max grew past threshold
      if (__any(pmax - m > DTHR)) {
        const float mn = fmaxf(m, pmax);
        const float alpha = __builtin_amdgcn_exp2f(m - mn);
        m = mn;
        l *= alpha;
#pragma unroll
        for (int dt = 0; dt < 4; ++dt)
#pragma unroll
          for (int r = 0; r < 4; ++r) o[dt][r] *= alpha;
      }

      // exp + hardware packed bf16 cvt; write P^T quads to wave-private LDS
      float rc[4];
#pragma unroll
      for (int ct = 0; ct < 4; ++ct) {
        float p0 = __builtin_amdgcn_exp2f(s[ct][0] - m);
        float p1 = __builtin_amdgcn_exp2f(s[ct][1] - m);
        float p2 = __builtin_amdgcn_exp2f(s[ct][2] - m);
        float p3 = __builtin_amdgcn_exp2f(s[ct][3] - m);
        rc[ct] = (p0 + p1) + (p2 + p3);
        uint2 w;
        w.x = cvtpk(p0, p1);
        w.y = cvtpk(p2, p3);
        *(uint2*)(pw + rl * ALDT + ct * 16 + lg * 4) = w;   // P[rl][ct*16+lg*4 ..+3]
      }
      l += (rc[0] + rc[1]) + (rc[2] + rc[3]);   // cross-lg reduce deferred to epilogue

      // O^T += V^T P^T : A-frag from lV, B-frag read back from wave-private P
#pragma unroll
      for (int kb2 = 0; kb2 < 2; ++kb2) {
        short8 pa = *(const short8*)(pw + rl * ALDT + kb2 * 32 + lg * 8);
        __builtin_amdgcn_s_setprio(1);
#pragma unroll
        for (int dt = 0; dt < 4; ++dt) {
          short8 av = *(const short8*)(bV + (dt * 16 + rl) * ALDT + kb2 * 32 + lg * 8);
          o[dt] = __builtin_amdgcn_mfma_f32_16x16x32_bf16(av, pa, o[dt], 0, 0, 0);
        }
        __builtin_amdgcn_s_setprio(0);
      }

      // one barrier per iter; lgkm only -> global prefetch stays in flight
      asm volatile("s_waitcnt lgkmcnt(0)" ::: "memory");
      __builtin_amdgcn_s_barrier();
    }

    // epilogue: finish deferred l-reduction, normalize, write O (4 contiguous d per lane)
    l += __shfl_xor(l, 16, 64);
    l += __shfl_xor(l, 32, 64);
    const float linv = __builtin_amdgcn_rcpf(l);
    const size_t obase = ((size_t)b * SEQ + qrow) * DIM + h * HD;
#pragma unroll
    for (int dt = 0; dt < 4; ++dt) {
      uint2 w;
      w.x = cvtpk(o[dt][0] * linv, o[dt][1] * linv);
      w.y = cvtpk(o[dt][2] * linv, o[dt][3] * linv);
      *(uint2*)(og + obase + dt * 16 + lg * 4) = w;
    }
  }
}

extern "C" void kernel_launch(void* const* d_in, const int* in_sizes, int n_in,
                              void* d_out, int out_size, void* d_ws, size_t ws_size,
                              hipStream_t stream) {
  const float* x = (const float*)d_in[0];
  const float* w_qkv = (const float*)d_in[1];
  const float* b_qkv = (const float*)d_in[2];
  const float* w_out = (const float*)d_in[3];
  const float* b_out = (const float*)d_in[4];
  const float* pos_bias = (const float*)d_in[5];
  float* out = (float*)d_out;

  u16* ws = (u16*)d_ws;
  u16* xb = ws;                                           // 4096*1024
  u16* wqkvb = xb + (size_t)MROWS * DIM;                  // 3072*1024 (w_qkv^T)
  u16* woutb = wqkvb + (size_t)NQKV * DIM;                // 1024*1024 (w_out^T)
  u16* qb = woutb + (size_t)DIM * DIM;                    // [b,h,t,d] (pre-scaled)
  u16* kbuf = qb + (size_t)BATCH * HEADS * SEQ * HD;      // [b,h,t,d]
  u16* vtb = kbuf + (size_t)BATCH * HEADS * SEQ * HD;     // [b,h,d,t]
  u16* attnb = xb;  // alias: xb dead after k_gemm_qkv (stream-serialized)

  k_prep<<<6144, 256, 0, stream>>>(x, xb, w_qkv, wqkvb, w_out, woutb);
  k_gemm_qkv<<<768, 256, 0, stream>>>(xb, wqkvb, b_qkv, pos_bias, qb, kbuf, vtb);
  k_attn<<<dim3(BATCH * HEADS * 16), 256, 0, stream>>>(qb, kbuf, vtb, attnb);
  k_gemm_out<<<512, 256, 0, stream>>>(attnb, woutb, b_out, out);
}

// Round 10
// 186.239 us; speedup vs baseline: 1.2983x; 1.0454x over previous
//
#include <hip/hip_runtime.h>

#define DIM 1024
#define HEADS 16
#define HD 64
#define BATCH 2
#define SEQ 2048
#define MROWS (BATCH*SEQ)   // 4096
#define NQKV (3*DIM)        // 3072
#define BK 32
#define NT (DIM/BK)         // 32 K-tiles
#define ALDT 72             // attn LDS row stride (u16)

typedef unsigned short u16;
typedef __attribute__((ext_vector_type(8))) short short8;  // 8 bf16 (4 VGPRs)
typedef __attribute__((ext_vector_type(4))) float f32x4;

#define QSCALE 0.1803368801111204f   // (1/sqrt(64)) * log2(e)
#define DTHR 11.5f                   // defer-max threshold (log2 units ~ e^8)

__device__ __forceinline__ u16 f2bf(float f) {
  unsigned u = __float_as_uint(f);
  u += 0x7FFFu + ((u >> 16) & 1u);   // RNE
  return (u16)(u >> 16);
}

__device__ __forceinline__ unsigned cvtpk(float lo, float hi) {
  unsigned r;
  asm("v_cvt_pk_bf16_f32 %0, %1, %2" : "=v"(r) : "v"(lo), "v"(hi));
  return r;
}

// async global->LDS, 16B per lane. LDS dest must be linear (base + lane*16).
__device__ __forceinline__ void gload16(const u16* g, u16* l) {
  __builtin_amdgcn_global_load_lds((const __attribute__((address_space(1))) unsigned int*)g,
                                   (__attribute__((address_space(3))) unsigned int*)l, 16, 0, 0);
}

// ---------------- fused prep: x->bf16 (2048 blks) + w_qkv^T (3072) + w_out^T (1024) ----
__global__ __launch_bounds__(256) void k_prep(
    const float* __restrict__ x, u16* __restrict__ xb,
    const float* __restrict__ wqkv, u16* __restrict__ oqkv,
    const float* __restrict__ wout, u16* __restrict__ oout) {
  __shared__ float tile[32][33];
  const int bid = blockIdx.x;
  const int tid = threadIdx.x;
  if (bid < 2048) {
    const int i = bid * 256 + tid;                 // 524288 = MROWS*DIM/8 exactly
    const float4* p = (const float4*)x + (size_t)i * 2;
    float4 a = p[0], b = p[1];
    short8 v;
    v[0] = (short)f2bf(a.x); v[1] = (short)f2bf(a.y);
    v[2] = (short)f2bf(a.z); v[3] = (short)f2bf(a.w);
    v[4] = (short)f2bf(b.x); v[5] = (short)f2bf(b.y);
    v[6] = (short)f2bf(b.z); v[7] = (short)f2bf(b.w);
    ((short8*)xb)[i] = v;
    return;
  }
  const float* in; u16* out; int C, c0, r0;
  if (bid < 2048 + 3072) {
    const int idx = bid - 2048;                    // 96 x-tiles, 32 y-tiles
    in = wqkv; out = oqkv; C = NQKV;
    c0 = (idx % 96) * 32; r0 = (idx / 96) * 32;
  } else {
    const int idx = bid - 5120;                    // 32 x 32
    in = wout; out = oout; C = DIM;
    c0 = (idx & 31) * 32; r0 = (idx >> 5) * 32;
  }
  const int tx = tid & 31, ty = tid >> 5;          // (32,8)
#pragma unroll
  for (int i = 0; i < 4; ++i)
    tile[ty + 8 * i][tx] = in[(size_t)(r0 + ty + 8 * i) * C + c0 + tx];
  __syncthreads();
#pragma unroll
  for (int i = 0; i < 4; ++i)
    out[(size_t)(c0 + ty + 8 * i) * DIM + r0 + tx] = f2bf(tile[tx][ty + 8 * i]);
}

// ---------------- QKV GEMM: 128x256 tile, 8 waves, triple-buffered gload_lds ----------
// grid = 384 (1D). 2D XCD tiling: xcd (xi,xj) owns 8 row-tiles x 6 col-tiles
// -> per-XCD L2 footprint = 2MB (A) + 1.5MB (B) < 4MB.
__global__ __launch_bounds__(512) void k_gemm_qkv(
    const u16* __restrict__ A, const u16* __restrict__ Bt,
    const float* __restrict__ bias, const float* __restrict__ posb,
    u16* __restrict__ qb, u16* __restrict__ kb, u16* __restrict__ vtb) {
  __shared__ u16 lds_[3 * 12288];   // 72 KB: per buf A[128][32] @0, B[256][32] @4096
  const int tid = threadIdx.x;
  const int lane = tid & 63;
  const int wid = tid >> 6;                 // 0..7
  const int wm = wid >> 2, wn = wid & 3;    // 2 x 4 wave grid, 64x64 per wave
  const int rl = lane & 15, lg = lane >> 4;
  const int csw = (rl >> 1) & 3;

  const int bid = blockIdx.x;
  const int xcd = bid & 7;
  const int s = bid >> 3;                   // 0..47
  const int xi = xcd >> 1, xj = xcd & 1;
  const int rowA0 = (xi * 8 + (s & 7)) * 128;
  const int rowB0 = (xj * 6 + (s >> 3)) * 256;

  const f32x4 fz = {0.f, 0.f, 0.f, 0.f};
  f32x4 acc[4][4];
#pragma unroll
  for (int i = 0; i < 4; ++i)
#pragma unroll
    for (int j = 0; j < 4; ++j) acc[i][j] = fz;

  const int srow = tid >> 2;                              // 0..127
  const int scol = ((tid & 3) ^ ((tid >> 3) & 3)) * 8;    // source-XOR swizzle
  const u16* gA = A + (size_t)(rowA0 + srow) * DIM + scol;
  const u16* gB0 = Bt + (size_t)(rowB0 + srow) * DIM + scol;
  const u16* gB1 = Bt + (size_t)(rowB0 + 128 + srow) * DIM + scol;

  auto stage = [&](int t, int j) {
    u16* d = lds_ + j * 12288;
    gload16(gA + t * BK, d + tid * 8);
    gload16(gB0 + t * BK, d + 4096 + tid * 8);
    gload16(gB1 + t * BK, d + 8192 + tid * 8);
  };
  auto compute = [&](int j) {
    const u16* bufA = lds_ + j * 12288;
    const u16* bufB = bufA + 4096;
    short8 af[4], bfr[4];
#pragma unroll
    for (int mf = 0; mf < 4; ++mf)
      af[mf] = *(const short8*)(bufA + (wm * 64 + mf * 16 + rl) * 32 + ((lg ^ csw) * 8));
#pragma unroll
    for (int nf = 0; nf < 4; ++nf)
      bfr[nf] = *(const short8*)(bufB + (wn * 64 + nf * 16 + rl) * 32 + ((lg ^ csw) * 8));
    __builtin_amdgcn_s_setprio(1);
#pragma unroll
    for (int mf = 0; mf < 4; ++mf)
#pragma unroll
      for (int nf = 0; nf < 4; ++nf)
        acc[mf][nf] = __builtin_amdgcn_mfma_f32_16x16x32_bf16(af[mf], bfr[nf], acc[mf][nf], 0, 0, 0);
    __builtin_amdgcn_s_setprio(0);
  };

  stage(0, 0);
  stage(1, 1);
  asm volatile("s_waitcnt vmcnt(3)" ::: "memory");
  __builtin_amdgcn_s_barrier();
#pragma unroll 3
  for (int t = 0; t < NT; ++t) {
    if (t + 2 < NT) {
      int nb = t + 2; nb -= (nb / 3) * 3;
      stage(t + 2, nb);
      compute(t - (t / 3) * 3);
      asm volatile("s_waitcnt vmcnt(3)" ::: "memory");
      __builtin_amdgcn_s_barrier();
    } else if (t == NT - 2) {
      compute(t - (t / 3) * 3);
      asm volatile("s_waitcnt vmcnt(0)" ::: "memory");
      __builtin_amdgcn_s_barrier();
    } else {
      compute(t - (t / 3) * 3);
    }
  }

#pragma unroll
  for (int mf = 0; mf < 4; ++mf) {
#pragma unroll
    for (int nf = 0; nf < 4; ++nf) {
#pragma unroll
      for (int r = 0; r < 4; ++r) {
        const int row = rowA0 + wm * 64 + mf * 16 + lg * 4 + r;
        const int col = rowB0 + wn * 64 + nf * 16 + rl;
        float v = acc[mf][nf][r] + bias[col];
        const int which = col >> 10;
        const int within = col & 1023;
        const int h = within >> 6, d = within & 63;
        const int bb = row >> 11, t = row & 2047;
        const size_t bh = (size_t)(bb * HEADS + h);
        if (which == 0) {
          v = (v + posb[within]) * QSCALE;
          qb[(bh * SEQ + t) * HD + d] = f2bf(v);
        } else if (which == 1) {
          kb[(bh * SEQ + t) * HD + d] = f2bf(v);
        } else {
          vtb[(bh * HD + d) * SEQ + t] = f2bf(v);
        }
      }
    }
  }
}

// ---------------- out GEMM: 128x64 tiles, quad-buffered, 1D grid + XCD swizzle ----------
__global__ __launch_bounds__(256) void k_gemm_out(
    const u16* __restrict__ A, const u16* __restrict__ Bt,
    const float* __restrict__ bias, float* __restrict__ out) {
  __shared__ u16 lds_[4 * 6144];
  const int tid = threadIdx.x;
  const int lane = tid & 63;
  const int wid = tid >> 6;
  const int wm = wid >> 1, wn = wid & 1;   // wave tile: 64x32
  const int bid_ = blockIdx.x;
  const int wg_ = (bid_ & 7) * 64 + (bid_ >> 3);   // 512 wgs
  const int rowB0 = (wg_ & 15) * 64;
  const int rowA0 = (wg_ >> 4) * 128;
  const int rl = lane & 15, lg = lane >> 4;
  const int csw = (rl >> 1) & 3;
  const f32x4 fz = {0.f, 0.f, 0.f, 0.f};
  f32x4 acc[4][2];
#pragma unroll
  for (int i = 0; i < 4; ++i)
#pragma unroll
    for (int j = 0; j < 2; ++j) acc[i][j] = fz;
  const int srow = tid >> 2;
  const int scol = ((tid & 3) ^ ((tid >> 3) & 3)) * 8;
  const u16* gA = A + (size_t)(rowA0 + srow) * DIM + scol;
  const u16* gB = Bt + (size_t)(rowB0 + srow) * DIM + scol;  // srow 0..63 valid rows
  auto stage = [&](int t, int j) {
    u16* d = lds_ + j * 6144;
    gload16(gA + t * BK, d + tid * 8);
    gload16(gA + (size_t)64 * DIM + t * BK, d + 2048 + tid * 8);
    gload16(gB + t * BK, d + 4096 + tid * 8);
  };
  auto compute = [&](int j) {
    const u16* bufA = lds_ + j * 6144;
    const u16* bufB = bufA + 4096;
    short8 af[4], bfr[2];
#pragma unroll
    for (int mf = 0; mf < 4; ++mf)
      af[mf] = *(const short8*)(bufA + (wm * 64 + mf * 16 + rl) * 32 + ((lg ^ csw) * 8));
#pragma unroll
    for (int nf = 0; nf < 2; ++nf)
      bfr[nf] = *(const short8*)(bufB + (wn * 32 + nf * 16 + rl) * 32 + ((lg ^ csw) * 8));
    __builtin_amdgcn_s_setprio(1);
#pragma unroll
    for (int mf = 0; mf < 4; ++mf)
#pragma unroll
      for (int nf = 0; nf < 2; ++nf)
        acc[mf][nf] = __builtin_amdgcn_mfma_f32_16x16x32_bf16(af[mf], bfr[nf], acc[mf][nf], 0, 0, 0);
    __builtin_amdgcn_s_setprio(0);
  };
  stage(0, 0);
  stage(1, 1);
  stage(2, 2);
  asm volatile("s_waitcnt vmcnt(6)" ::: "memory");
  __builtin_amdgcn_s_barrier();
#pragma unroll 4
  for (int t = 0; t < NT; ++t) {
    if (t + 3 < NT) {
      stage(t + 3, (t + 3) & 3);
      compute(t & 3);
      asm volatile("s_waitcnt vmcnt(6)" ::: "memory");
      __builtin_amdgcn_s_barrier();
    } else if (t == NT - 3) {
      compute(t & 3);
      asm volatile("s_waitcnt vmcnt(3)" ::: "memory");
      __builtin_amdgcn_s_barrier();
    } else if (t == NT - 2) {
      compute(t & 3);
      asm volatile("s_waitcnt vmcnt(0)" ::: "memory");
      __builtin_amdgcn_s_barrier();
    } else {
      compute(t & 3);
    }
  }

#pragma unroll
  for (int mf = 0; mf < 4; ++mf)
#pragma unroll
    for (int nf = 0; nf < 2; ++nf)
#pragma unroll
      for (int r = 0; r < 4; ++r) {
        const int row = rowA0 + wm * 64 + mf * 16 + lg * 4 + r;
        const int col = rowB0 + wn * 32 + nf * 16 + rl;
        out[(size_t)row * DIM + col] = acc[mf][nf][r] + bias[col];
      }
}

// ---------------- flash attention (causal), swapped-QK^T, paired + XCD-affine ----------
// R7-proven structure: KVBLK=64, dbuf K/V, lP regroup, one lgkm-only barrier/iter.
__global__ __launch_bounds__(256) void k_attn(
    const u16* __restrict__ qg, const u16* __restrict__ kg, const u16* __restrict__ vg,
    u16* __restrict__ og) {
  __shared__ u16 lK[2][64 * ALDT];   // [kv][d]
  __shared__ u16 lV[2][64 * ALDT];   // [d][kv]  (V^T)
  __shared__ u16 lP[4 * 16 * ALDT];  // wave-private P^T regroup buffers
  const int tid = threadIdx.x;
  const int lane = tid & 63;
  const int wid = tid >> 6;
  const int rl = lane & 15, lg = lane >> 4;
  const int bh = blockIdx.x & 31;
  const int pair = blockIdx.x >> 5;
  const int b = bh >> 4, h = bh & 15;

  const u16* gK = kg + (size_t)bh * SEQ * HD;
  const u16* gV = vg + (size_t)bh * HD * SEQ;
  const int sr = tid >> 3;          // 0..31
  const int sc = (tid & 7) * 8;     // 0..56
  u16* pw = lP + wid * 16 * ALDT;

#pragma unroll 1
  for (int half = 0; half < 2; ++half) {
    const int qt = half ? pair : (31 - pair);
    const int qrow = qt * 64 + wid * 16 + rl;   // this lane's q index
    const u16* qptr = qg + ((size_t)bh * SEQ + qrow) * HD + lg * 8;
    const short8 aq0 = *(const short8*)(qptr);
    const short8 aq1 = *(const short8*)(qptr + 32);

    const f32x4 fz = {0.f, 0.f, 0.f, 0.f};
    f32x4 o[4];
#pragma unroll
    for (int dt = 0; dt < 4; ++dt) o[dt] = fz;
    float m = -1e30f, l = 0.f;

    // prologue: tile0 -> buf0; prefetch tile1 into regs
    int4 rka = *(const int4*)(gK + (size_t)sr * HD + sc);
    int4 rkb = *(const int4*)(gK + (size_t)(sr + 32) * HD + sc);
    int4 rva = *(const int4*)(gV + (size_t)sr * SEQ + sc);
    int4 rvb = *(const int4*)(gV + (size_t)(sr + 32) * SEQ + sc);
    *(int4*)(lK[0] + sr * ALDT + sc) = rka;
    *(int4*)(lK[0] + (sr + 32) * ALDT + sc) = rkb;
    *(int4*)(lV[0] + sr * ALDT + sc) = rva;
    *(int4*)(lV[0] + (sr + 32) * ALDT + sc) = rvb;
    if (qt > 0) {
      rka = *(const int4*)(gK + (size_t)(64 + sr) * HD + sc);
      rkb = *(const int4*)(gK + (size_t)(64 + sr + 32) * HD + sc);
      rva = *(const int4*)(gV + (size_t)sr * SEQ + 64 + sc);
      rvb = *(const int4*)(gV + (size_t)(sr + 32) * SEQ + 64 + sc);
    }
    asm volatile("s_waitcnt lgkmcnt(0)" ::: "memory");
    __builtin_amdgcn_s_barrier();

    for (int kt = 0; kt <= qt; ++kt) {
      const int cur = kt & 1;
      // stage tile kt+1 into alternate buffer; prefetch tile kt+2 into regs
      if (kt < qt) {
        u16* dK = lK[cur ^ 1];
        u16* dV = lV[cur ^ 1];
        *(int4*)(dK + sr * ALDT + sc) = rka;
        *(int4*)(dK + (sr + 32) * ALDT + sc) = rkb;
        *(int4*)(dV + sr * ALDT + sc) = rva;
        *(int4*)(dV + (sr + 32) * ALDT + sc) = rvb;
        if (kt + 2 <= qt) {
          const int kv2 = (kt + 2) * 64;
          rka = *(const int4*)(gK + (size_t)(kv2 + sr) * HD + sc);
          rkb = *(const int4*)(gK + (size_t)(kv2 + sr + 32) * HD + sc);
          rva = *(const int4*)(gV + (size_t)sr * SEQ + kv2 + sc);
          rvb = *(const int4*)(gV + (size_t)(sr + 32) * SEQ + kv2 + sc);
        }
      }
      const u16* bK = lK[cur];
      const u16* bV = lV[cur];

      // S^T = K Q^T : lane holds S[q=rl][kv = ct*16 + lg*4 + r]
      f32x4 s[4];
#pragma unroll
      for (int ct = 0; ct < 4; ++ct) s[ct] = fz;
      __builtin_amdgcn_s_setprio(1);
#pragma unroll
      for (int ct = 0; ct < 4; ++ct) {
        short8 ak0 = *(const short8*)(bK + (ct * 16 + rl) * ALDT + lg * 8);
        short8 ak1 = *(const short8*)(bK + (ct * 16 + rl) * ALDT + 32 + lg * 8);
        s[ct] = __builtin_amdgcn_mfma_f32_16x16x32_bf16(ak0, aq0, s[ct], 0, 0, 0);
        s[ct] = __builtin_amdgcn_mfma_f32_16x16x32_bf16(ak1, aq1, s[ct], 0, 0, 0);
      }
      __builtin_amdgcn_s_setprio(0);

      if (kt == qt) {   // diagonal tile: causal mask
#pragma unroll
        for (int ct = 0; ct < 4; ++ct)
#pragma unroll
          for (int r = 0; r < 4; ++r)
            if (kt * 64 + ct * 16 + lg * 4 + r > qrow) s[ct][r] = -1e30f;
      }

      // tree max (depth 4)
      float cm[4];
#pragma unroll
      for (int ct = 0; ct < 4; ++ct)
        cm[ct] = fmaxf(fmaxf(s[ct][0], s[ct][1]), fmaxf(s[ct][2], s[ct][3]));
      float pmax = fmaxf(fmaxf(cm[0], cm[1]), fmaxf(cm[2], cm[3]));
      pmax = fmaxf(pmax, __shfl_xor(pmax, 16, 64));
      pmax = fmaxf(pmax, __shfl_xor(pmax, 32, 64));

      // defer-max (T13): only rescale when max grew past threshold
      if (__any(pmax - m > DTHR)) {
        const float mn = fmaxf(m, pmax);
        const float alpha = __builtin_amdgcn_exp2f(m - mn);
        m = mn;
        l *= alpha;
#pragma unroll
        for (int dt = 0; dt < 4; ++dt)
#pragma unroll
          for (int r = 0; r < 4; ++r) o[dt][r] *= alpha;
      }

      // exp + hardware packed bf16 cvt; write P^T quads to wave-private LDS
      float rc[4];
#pragma unroll
      for (int ct = 0; ct < 4; ++ct) {
        float p0 = __builtin_amdgcn_exp2f(s[ct][0] - m);
        float p1 = __builtin_amdgcn_exp2f(s[ct][1] - m);
        float p2 = __builtin_amdgcn_exp2f(s[ct][2] - m);
        float p3 = __builtin_amdgcn_exp2f(s[ct][3] - m);
        rc[ct] = (p0 + p1) + (p2 + p3);
        uint2 w;
        w.x = cvtpk(p0, p1);
        w.y = cvtpk(p2, p3);
        *(uint2*)(pw + rl * ALDT + ct * 16 + lg * 4) = w;   // P[rl][ct*16+lg*4 ..+3]
      }
      l += (rc[0] + rc[1]) + (rc[2] + rc[3]);   // cross-lg reduce deferred to epilogue

      // O^T += V^T P^T : A-frag from lV, B-frag read back from wave-private P
#pragma unroll
      for (int kb2 = 0; kb2 < 2; ++kb2) {
        short8 pa = *(const short8*)(pw + rl * ALDT + kb2 * 32 + lg * 8);
        __builtin_amdgcn_s_setprio(1);
#pragma unroll
        for (int dt = 0; dt < 4; ++dt) {
          short8 av = *(const short8*)(bV + (dt * 16 + rl) * ALDT + kb2 * 32 + lg * 8);
          o[dt] = __builtin_amdgcn_mfma_f32_16x16x32_bf16(av, pa, o[dt], 0, 0, 0);
        }
        __builtin_amdgcn_s_setprio(0);
      }

      // one barrier per iter; lgkm only -> global prefetch stays in flight
      asm volatile("s_waitcnt lgkmcnt(0)" ::: "memory");
      __builtin_amdgcn_s_barrier();
    }

    // epilogue: finish deferred l-reduction, normalize, write O (4 contiguous d per lane)
    l += __shfl_xor(l, 16, 64);
    l += __shfl_xor(l, 32, 64);
    const float linv = __builtin_amdgcn_rcpf(l);
    const size_t obase = ((size_t)b * SEQ + qrow) * DIM + h * HD;
#pragma unroll
    for (int dt = 0; dt < 4; ++dt) {
      uint2 w;
      w.x = cvtpk(o[dt][0] * linv, o[dt][1] * linv);
      w.y = cvtpk(o[dt][2] * linv, o[dt][3] * linv);
      *(uint2*)(og + obase + dt * 16 + lg * 4) = w;
    }
  }
}

extern "C" void kernel_launch(void* const* d_in, const int* in_sizes, int n_in,
                              void* d_out, int out_size, void* d_ws, size_t ws_size,
                              hipStream_t stream) {
  const float* x = (const float*)d_in[0];
  const float* w_qkv = (const float*)d_in[1];
  const float* b_qkv = (const float*)d_in[2];
  const float* w_out = (const float*)d_in[3];
  const float* b_out = (const float*)d_in[4];
  const float* pos_bias = (const float*)d_in[5];
  float* out = (float*)d_out;

  u16* ws = (u16*)d_ws;
  u16* xb = ws;                                           // 4096*1024
  u16* wqkvb = xb + (size_t)MROWS * DIM;                  // 3072*1024 (w_qkv^T)
  u16* woutb = wqkvb + (size_t)NQKV * DIM;                // 1024*1024 (w_out^T)
  u16* qb = woutb + (size_t)DIM * DIM;                    // [b,h,t,d] (pre-scaled)
  u16* kbuf = qb + (size_t)BATCH * HEADS * SEQ * HD;      // [b,h,t,d]
  u16* vtb = kbuf + (size_t)BATCH * HEADS * SEQ * HD;     // [b,h,d,t]
  u16* attnb = xb;  // alias: xb dead after k_gemm_qkv (stream-serialized)

  k_prep<<<6144, 256, 0, stream>>>(x, xb, w_qkv, wqkvb, w_out, woutb);
  k_gemm_qkv<<<384, 512, 0, stream>>>(xb, wqkvb, b_qkv, pos_bias, qb, kbuf, vtb);
  k_attn<<<dim3(BATCH * HEADS * 16), 256, 0, stream>>>(qb, kbuf, vtb, attnb);
  k_gemm_out<<<512, 256, 0, stream>>>(attnb, woutb, b_out, out);
}